// Round 1
// baseline (348.975 us; speedup 1.0000x reference)
//
#include <hip/hip_runtime.h>
#include <math.h>

#define WAVE 64

// ---- constants from the reference ----
#define KC        2.2281692032865347f   // 7/pi
#define H         0.05f
#define INV_H2    400.0f                // 1/h^2
#define INV_H3    8000.0f               // 1/h^3
#define EPS_REF   0.00025f              // h^2 * 0.1
#define K_OUT     0.24261080f           // 2*h*DELTA*C0 = 0.01 * 10*sqrt(2*9.81*0.3)
#define REST_RHO  1000.0f

// Wave-level segmented reduction: keys (= i[e]) are sorted, so equal keys are
// contiguous. Inclusive segmented scan via shfl_up; only segment-tail lanes
// issue atomics. Inactive lanes pass key=-1, v=0.
template<int NV>
__device__ __forceinline__ void seg_reduce_atomic(int key, float* v, float* __restrict__ base) {
    const int lane = threadIdx.x & (WAVE - 1);
#pragma unroll
    for (int d = 1; d < WAVE; d <<= 1) {
        int okey = __shfl_up(key, d, WAVE);
        float ov[NV];
#pragma unroll
        for (int c = 0; c < NV; ++c) ov[c] = __shfl_up(v[c], d, WAVE);
        if (lane >= d && okey == key) {
#pragma unroll
            for (int c = 0; c < NV; ++c) v[c] += ov[c];
        }
    }
    int nkey = __shfl_down(key, 1, WAVE);
    if ((lane == WAVE - 1 || nkey != key) && key >= 0) {
#pragma unroll
        for (int c = 0; c < NV; ++c) atomicAdd(base + (size_t)key * NV + c, v[c]);
    }
}

__device__ __forceinline__ float wendland_dkdq(float q) {
    float omq = 1.0f - q;
    return -20.0f * q * omq * omq * omq * KC;
}

// Pass 1: M[i] += s * dir dir^T, s = -2*Vj*q*dkdq/h^2  (symmetric: store m00,m01,m11)
__global__ void k_edge_M(const float2* __restrict__ dirs, const float* __restrict__ qarr,
                         const int* __restrict__ ei, const int* __restrict__ ej,
                         const float* __restrict__ vol, float* __restrict__ M, int E) {
    int e = blockIdx.x * blockDim.x + threadIdx.x;
    int key = -1;
    float v[3] = {0.f, 0.f, 0.f};
    if (e < E) {
        key = ei[e];
        float q = qarr[e];
        float2 d = dirs[e];
        float Vj = vol[ej[e]];
        float s = -2.0f * Vj * q * wendland_dkdq(q) * INV_H2;  // >= 0
        v[0] = s * d.x * d.x;
        v[1] = s * d.x * d.y;
        v[2] = s * d.y * d.y;
    }
    seg_reduce_atomic<3>(key, v, M);
}

// Pass 2: per-node pseudo-inverse of symmetric PSD 2x2, JAX pinv cutoff semantics.
__global__ void k_node_pinv(float* __restrict__ M, int N) {
    int n = blockIdx.x * blockDim.x + threadIdx.x;
    if (n >= N) return;
    float a = M[3 * n + 0], b = M[3 * n + 1], c = M[3 * n + 2];
    float half_tr   = 0.5f * (a + c);
    float half_diff = 0.5f * (a - c);
    float disc = sqrtf(half_diff * half_diff + b * b);
    float l1 = half_tr + disc;   // l1 >= l2
    float l2 = half_tr - disc;
    // jnp.linalg.pinv default: rcond = 10*max(2,2)*eps_f32 = 2.3841858e-6
    float smax = fmaxf(fabsf(l1), fabsf(l2));
    float cutoff = 2.3841858e-6f * smax;
    float i00 = 0.f, i01 = 0.f, i11 = 0.f;
    if (fabsf(l2) > cutoff) {
        // full rank: plain inverse
        float det = a * c - b * b;
        float inv = 1.0f / det;
        i00 =  c * inv;
        i01 = -b * inv;
        i11 =  a * inv;
    } else if (fabsf(l1) > cutoff) {
        // rank 1: pinv = (1/l1) v v^T, v eigenvector of l1 (pick better-conditioned row)
        float vax = b,      vay = l1 - a;       // from row 0
        float vbx = l1 - c, vby = b;            // from row 1
        float na = vax * vax + vay * vay;
        float nb = vbx * vbx + vby * vby;
        float vx, vy, n2;
        if (nb >= na) { vx = vbx; vy = vby; n2 = nb; }
        else          { vx = vax; vy = vay; n2 = na; }
        float inv = 1.0f / (l1 * n2);
        i00 = vx * vx * inv;
        i01 = vx * vy * inv;
        i11 = vy * vy * inv;
    }
    M[3 * n + 0] = i00;
    M[3 * n + 1] = i01;
    M[3 * n + 2] = i11;
}

// Pass 3: gradRho[i] += 2*rho_ba*Vj * grad, with change-filter fallback to gradW.
__global__ void k_edge_gradRho(const float2* __restrict__ dirs, const float* __restrict__ qarr,
                               const int* __restrict__ ei, const int* __restrict__ ej,
                               const float* __restrict__ vol, const float* __restrict__ dens,
                               const float* __restrict__ Li, float* __restrict__ gradRho, int E) {
    int e = blockIdx.x * blockDim.x + threadIdx.x;
    int key = -1;
    float v[2] = {0.f, 0.f};
    if (e < E) {
        key = ei[e];
        int jj = ej[e];
        float q = qarr[e];
        float2 d = dirs[e];
        float w = wendland_dkdq(q) * INV_H3;
        float gwx = d.x * w, gwy = d.y * w;
        float li00 = Li[3 * key + 0], li01 = Li[3 * key + 1], li11 = Li[3 * key + 2];
        float gx = li00 * gwx + li01 * gwy;
        float gy = li01 * gwx + li11 * gwy;
        float dwij_mag = fabsf(gwx) + fabsf(gwy);
        float norm_mag = fabsf(gx) + fabsf(gy);
        float change = fabsf(norm_mag - dwij_mag) / (dwij_mag + 1e-4f * H);
        if (!(change < 0.1f)) { gx = gwx; gy = gwy; }   // matches jnp.where (NaN -> gradW)
        float val = 2.0f * REST_RHO * (dens[jj] - dens[key]) * vol[jj];
        v[0] = val * gx;
        v[1] = val * gy;
    }
    seg_reduce_atomic<2>(key, v, gradRho);
}

// Pass 4: deltaSPH density diffusion into out[i].
__global__ void k_edge_out(const float2* __restrict__ dirs, const float* __restrict__ qarr,
                           const int* __restrict__ ei, const int* __restrict__ ej,
                           const float* __restrict__ vol, const float* __restrict__ dens,
                           const float2* __restrict__ gradRho, float* __restrict__ out, int E) {
    int e = blockIdx.x * blockDim.x + threadIdx.x;
    int key = -1;
    float v[1] = {0.f};
    if (e < E) {
        key = ei[e];
        int jj = ej[e];
        float q = qarr[e];
        float2 d = dirs[e];
        float w = wendland_dkdq(q) * INV_H3;
        float gwx = d.x * w, gwy = d.y * w;
        float rx = -d.x * q * H, ry = -d.y * q * H;
        float rji2 = rx * rx + ry * ry + EPS_REF;
        float gradTerm = (gwx * rx + gwy * ry) / rji2;
        float2 gi = gradRho[key];
        float2 gj = gradRho[jj];
        float densityTerm = 0.5f * ((gi.x + gj.x) * rx + (gi.y + gj.y) * ry);
        float rho_ba = REST_RHO * (dens[jj] - dens[key]);
        float prod = (rho_ba + densityTerm) * gradTerm;
        v[0] = prod * vol[jj] * K_OUT;
    }
    seg_reduce_atomic<1>(key, v, out);
}

extern "C" void kernel_launch(void* const* d_in, const int* in_sizes, int n_in,
                              void* d_out, int out_size, void* d_ws, size_t ws_size,
                              hipStream_t stream) {
    // inputs: 0 fluidPosition (unused), 1 fluidVolume[N], 2 fluidDensity[N],
    //         3 distances[E,2], 4 radialDistances[E], 5 i[E], 6 j[E]
    const float*  vol  = (const float*)d_in[1];
    const float*  dens = (const float*)d_in[2];
    const float2* dirs = (const float2*)d_in[3];
    const float*  qarr = (const float*)d_in[4];
    const int*    ei   = (const int*)d_in[5];
    const int*    ej   = (const int*)d_in[6];
    const int N = in_sizes[1];
    const int E = in_sizes[4];

    float* M       = (float*)d_ws;           // N*3 floats: m00,m01,m11 -> becomes Li in place
    float* gradRho = M + (size_t)N * 3;      // N*2 floats
    float* out     = (float*)d_out;

    // ws/out are poisoned 0xAA before every timed call -> zero what we accumulate into.
    hipMemsetAsync(M, 0, (size_t)N * 5 * sizeof(float), stream);
    hipMemsetAsync(out, 0, (size_t)N * sizeof(float), stream);

    const int tb = 256;
    const int gE = (E + tb - 1) / tb;
    const int gN = (N + tb - 1) / tb;

    k_edge_M      <<<gE, tb, 0, stream>>>(dirs, qarr, ei, ej, vol, M, E);
    k_node_pinv   <<<gN, tb, 0, stream>>>(M, N);
    k_edge_gradRho<<<gE, tb, 0, stream>>>(dirs, qarr, ei, ej, vol, dens, M, gradRho, E);
    k_edge_out    <<<gE, tb, 0, stream>>>(dirs, qarr, ei, ej, vol, dens, (const float2*)gradRho, out, E);
}

// Round 2
// 289.635 us; speedup vs baseline: 1.2049x; 1.2049x over previous
//
#include <hip/hip_runtime.h>
#include <math.h>

#define WAVE 64

// ---- constants from the reference ----
#define KC        2.2281692032865347f   // 7/pi
#define H         0.05f
#define INV_H2    400.0f                // 1/h^2
#define INV_H3    8000.0f               // 1/h^3
#define EPS_REF   0.00025f              // h^2 * 0.1
#define K_OUT     0.24261080f           // 2*h*DELTA*C0
#define REST_RHO  1000.0f

__device__ __forceinline__ float wendland_dkdq(float q) {
    float omq = 1.0f - q;
    return -20.0f * q * omq * omq * omq * KC;
}

// ---------------------------------------------------------------------------
// 4-edge-per-lane segmented reduction into base[key*NV+c].
// Keys are globally sorted ascending; within a lane k[0]<=k[1]<=k[2]<=k[3].
// Strategy: first-run (key k[0]) may extend into previous lanes -> flushed
// with the carry from the wave scan; middle runs are fully contained in the
// lane -> direct atomics (rare); last-run (key k[3]) participates in the
// wave-level segmented inclusive scan; segment tails issue atomics.
// Invalid edges must be encoded as key == last valid key (or -1) with v == 0.
// ---------------------------------------------------------------------------
template<int NV>
__device__ __forceinline__ void seg_reduce4(const int k[4], float v[4][NV],
                                            float* __restrict__ base) {
    const int lane = threadIdx.x & (WAVE - 1);
    const int k0 = k[0], k3 = k[3];
    const bool split = (k0 != k3);
    const int firstLen  = (k[1]==k0) ? ((k[2]==k0) ? ((k[3]==k0)?4:3) : 2) : 1;
    const int lastStart = (k[2]==k3) ? ((k[1]==k3) ? ((k[0]==k3)?0:1) : 2) : 3;

    float vin[NV], vfirst[NV];
#pragma unroll
    for (int c = 0; c < NV; ++c) {
        float s = v[3][c];
        if (lastStart <= 2) s += v[2][c];
        if (lastStart <= 1) s += v[1][c];
        if (lastStart == 0) s += v[0][c];
        vin[c] = s;
        float f = v[0][c];
        if (firstLen >= 2) f += v[1][c];
        if (firstLen >= 3) f += v[2][c];
        if (firstLen >= 4) f += v[3][c];
        vfirst[c] = f;
    }

    // middle runs: fully contained in this lane
#pragma unroll
    for (int idx = 1; idx <= 2; ++idx) {
        if (idx >= firstLen && idx < lastStart && k[idx] >= 0) {
#pragma unroll
            for (int c = 0; c < NV; ++c)
                atomicAdd(base + (size_t)k[idx] * NV + c, v[idx][c]);
        }
    }

    // wave-level segmented inclusive scan on (k3, vin)
    float S[NV];
#pragma unroll
    for (int c = 0; c < NV; ++c) S[c] = vin[c];
    const int klast = k3;
#pragma unroll
    for (int d = 1; d < WAVE; d <<= 1) {
        int okey = __shfl_up(klast, d, WAVE);
        float ov[NV];
#pragma unroll
        for (int c = 0; c < NV; ++c) ov[c] = __shfl_up(S[c], d, WAVE);
        if (lane >= d && okey == klast) {
#pragma unroll
            for (int c = 0; c < NV; ++c) S[c] += ov[c];
        }
    }

    // first-run flush (segment ending inside this lane)
    const int prevk = __shfl_up(klast, 1, WAVE);
    float P[NV];
#pragma unroll
    for (int c = 0; c < NV; ++c) P[c] = __shfl_up(S[c], 1, WAVE);
    if (split && k0 >= 0) {
        const bool carry = (lane > 0 && prevk == k0);
#pragma unroll
        for (int c = 0; c < NV; ++c)
            atomicAdd(base + (size_t)k0 * NV + c, vfirst[c] + (carry ? P[c] : 0.f));
    }

    // last-run tail flush
    const int nk0 = __shfl_down(k0, 1, WAVE);
    const bool tail = (lane == WAVE - 1) || (nk0 != klast);
    if (tail && klast >= 0) {
#pragma unroll
        for (int c = 0; c < NV; ++c)
            atomicAdd(base + (size_t)klast * NV + c, S[c]);
    }
}

struct Edge4 {
    int   i[4], j[4];
    float q[4], dx[4], dy[4];
};

__device__ __forceinline__ void load_edge4(int t, int E,
        const int* __restrict__ ei, const int* __restrict__ ej,
        const float* __restrict__ qarr, const float2* __restrict__ dirs, Edge4& ed) {
    const long e0 = 4L * t;
    if (e0 + 3 < (long)E) {
        int4   i4 = ((const int4*)ei)[t];
        int4   j4 = ((const int4*)ej)[t];
        float4 q4 = ((const float4*)qarr)[t];
        float4 dA = ((const float4*)dirs)[2 * t];
        float4 dB = ((const float4*)dirs)[2 * t + 1];
        ed.i[0]=i4.x; ed.i[1]=i4.y; ed.i[2]=i4.z; ed.i[3]=i4.w;
        ed.j[0]=j4.x; ed.j[1]=j4.y; ed.j[2]=j4.z; ed.j[3]=j4.w;
        ed.q[0]=q4.x; ed.q[1]=q4.y; ed.q[2]=q4.z; ed.q[3]=q4.w;
        ed.dx[0]=dA.x; ed.dy[0]=dA.y; ed.dx[1]=dA.z; ed.dy[1]=dA.w;
        ed.dx[2]=dB.x; ed.dy[2]=dB.y; ed.dx[3]=dB.z; ed.dy[3]=dB.w;
    } else {
        int lastk = -1;
#pragma unroll
        for (int u = 0; u < 4; ++u) {
            long e = e0 + u;
            if (e < (long)E) {
                ed.i[u] = ei[e]; ed.j[u] = ej[e]; ed.q[u] = qarr[e];
                float2 d = dirs[e]; ed.dx[u] = d.x; ed.dy[u] = d.y;
                lastk = ed.i[u];
            } else {
                ed.i[u] = lastk; ed.j[u] = 0; ed.q[u] = 0.f;
                ed.dx[u] = 0.f; ed.dy[u] = 0.f;   // q=0 -> zero contribution
            }
        }
    }
}

// Pass 1: M[i] += s * dir dir^T  (symmetric: m00,m01,m11)
__global__ void k_edge_M4(const float2* __restrict__ dirs, const float* __restrict__ qarr,
                          const int* __restrict__ ei, const int* __restrict__ ej,
                          const float* __restrict__ vol, float* __restrict__ M, int E) {
    int t = blockIdx.x * blockDim.x + threadIdx.x;
    Edge4 ed; load_edge4(t, E, ei, ej, qarr, dirs, ed);
    float vj[4];
#pragma unroll
    for (int u = 0; u < 4; ++u) vj[u] = vol[ed.j[u]];   // 4 independent gathers
    int k[4]; float v[4][3];
#pragma unroll
    for (int u = 0; u < 4; ++u) {
        float q = ed.q[u];
        float s = -2.0f * vj[u] * q * wendland_dkdq(q) * INV_H2;  // >= 0
        k[u] = ed.i[u];
        v[u][0] = s * ed.dx[u] * ed.dx[u];
        v[u][1] = s * ed.dx[u] * ed.dy[u];
        v[u][2] = s * ed.dy[u] * ed.dy[u];
    }
    seg_reduce4<3>(k, v, M);
}

// Pass 2: symmetric PSD 2x2 pinv (JAX cutoff semantics) + pack vd=(vol,dens)
__global__ void k_node_pinv_pack(float* __restrict__ M, const float* __restrict__ vol,
                                 const float* __restrict__ dens, float2* __restrict__ vd, int N) {
    int n = blockIdx.x * blockDim.x + threadIdx.x;
    if (n >= N) return;
    vd[n] = make_float2(vol[n], dens[n]);
    float a = M[3*n+0], b = M[3*n+1], c = M[3*n+2];
    float half_tr   = 0.5f * (a + c);
    float half_diff = 0.5f * (a - c);
    float disc = sqrtf(half_diff * half_diff + b * b);
    float l1 = half_tr + disc, l2 = half_tr - disc;
    float smax = fmaxf(fabsf(l1), fabsf(l2));
    float cutoff = 2.3841858e-6f * smax;   // rcond = 10*max(2,2)*eps_f32
    float i00 = 0.f, i01 = 0.f, i11 = 0.f;
    if (fabsf(l2) > cutoff) {
        float inv = 1.0f / (a * c - b * b);
        i00 =  c * inv; i01 = -b * inv; i11 = a * inv;
    } else if (fabsf(l1) > cutoff) {
        float vax = b,      vay = l1 - a;
        float vbx = l1 - c, vby = b;
        float na = vax*vax + vay*vay, nb = vbx*vbx + vby*vby;
        float vx, vy, n2;
        if (nb >= na) { vx = vbx; vy = vby; n2 = nb; }
        else          { vx = vax; vy = vay; n2 = na; }
        float inv = 1.0f / (l1 * n2);
        i00 = vx*vx*inv; i01 = vx*vy*inv; i11 = vy*vy*inv;
    }
    M[3*n+0] = i00; M[3*n+1] = i01; M[3*n+2] = i11;
}

// Pass 3: gradRho[i] += 2*rho_ba*Vj * grad (with change-filter fallback)
__global__ void k_edge_gradRho4(const float2* __restrict__ dirs, const float* __restrict__ qarr,
                                const int* __restrict__ ei, const int* __restrict__ ej,
                                const float2* __restrict__ vd, const float* __restrict__ Li,
                                float* __restrict__ gradRho, int E) {
    int t = blockIdx.x * blockDim.x + threadIdx.x;
    Edge4 ed; load_edge4(t, E, ei, ej, qarr, dirs, ed);
    float2 vdj[4];
#pragma unroll
    for (int u = 0; u < 4; ++u) vdj[u] = vd[ed.j[u]];   // 4 independent gathers
    int k[4]; float v[4][2];
#pragma unroll
    for (int u = 0; u < 4; ++u) {
        int key = ed.i[u];
        k[u] = key;
        v[u][0] = 0.f; v[u][1] = 0.f;
        if (key >= 0) {
            float q = ed.q[u];
            float w = wendland_dkdq(q) * INV_H3;
            float gwx = ed.dx[u] * w, gwy = ed.dy[u] * w;
            float li00 = Li[3*key+0], li01 = Li[3*key+1], li11 = Li[3*key+2];
            float gx = li00 * gwx + li01 * gwy;
            float gy = li01 * gwx + li11 * gwy;
            float dwij_mag = fabsf(gwx) + fabsf(gwy);
            float norm_mag = fabsf(gx) + fabsf(gy);
            float change = fabsf(norm_mag - dwij_mag) / (dwij_mag + 1e-4f * H);
            if (!(change < 0.1f)) { gx = gwx; gy = gwy; }   // NaN -> fallback, matches jnp.where
            float dens_i = vd[key].y;
            float val = 2.0f * REST_RHO * (vdj[u].y - dens_i) * vdj[u].x;
            v[u][0] = val * gx;
            v[u][1] = val * gy;
        }
    }
    seg_reduce4<2>(k, v, gradRho);
}

// Pack nd = (vol, dens, gradRho.x, gradRho.y) so pass 4 needs one gather/edge
__global__ void k_pack_nd(const float* __restrict__ vol, const float* __restrict__ dens,
                          const float2* __restrict__ gradRho, float4* __restrict__ nd, int N) {
    int n = blockIdx.x * blockDim.x + threadIdx.x;
    if (n >= N) return;
    float2 g = gradRho[n];
    nd[n] = make_float4(vol[n], dens[n], g.x, g.y);
}

// Pass 4: deltaSPH density diffusion into out[i]
__global__ void k_edge_out4(const float2* __restrict__ dirs, const float* __restrict__ qarr,
                            const int* __restrict__ ei, const int* __restrict__ ej,
                            const float4* __restrict__ nd, float* __restrict__ out, int E) {
    int t = blockIdx.x * blockDim.x + threadIdx.x;
    Edge4 ed; load_edge4(t, E, ei, ej, qarr, dirs, ed);
    float4 ndj[4];
#pragma unroll
    for (int u = 0; u < 4; ++u) ndj[u] = nd[ed.j[u]];   // 4 independent 16B gathers
    int k[4]; float v[4][1];
#pragma unroll
    for (int u = 0; u < 4; ++u) {
        int key = ed.i[u];
        k[u] = key;
        v[u][0] = 0.f;
        if (key >= 0) {
            float4 ndi = nd[key];                        // run-shared line, L1-resident
            float q = ed.q[u];
            float w = wendland_dkdq(q) * INV_H3;
            float gwx = ed.dx[u] * w, gwy = ed.dy[u] * w;
            float rx = -ed.dx[u] * q * H, ry = -ed.dy[u] * q * H;
            float rji2 = rx * rx + ry * ry + EPS_REF;
            float gradTerm = (gwx * rx + gwy * ry) / rji2;
            float densityTerm = 0.5f * ((ndi.z + ndj[u].z) * rx + (ndi.w + ndj[u].w) * ry);
            float rho_ba = REST_RHO * (ndj[u].y - ndi.y);
            v[u][0] = (rho_ba + densityTerm) * gradTerm * ndj[u].x * K_OUT;
        }
    }
    seg_reduce4<1>(k, v, out);
}

extern "C" void kernel_launch(void* const* d_in, const int* in_sizes, int n_in,
                              void* d_out, int out_size, void* d_ws, size_t ws_size,
                              hipStream_t stream) {
    // inputs: 0 fluidPosition (unused), 1 fluidVolume[N], 2 fluidDensity[N],
    //         3 distances[E,2], 4 radialDistances[E], 5 i[E], 6 j[E]
    const float*  vol  = (const float*)d_in[1];
    const float*  dens = (const float*)d_in[2];
    const float2* dirs = (const float2*)d_in[3];
    const float*  qarr = (const float*)d_in[4];
    const int*    ei   = (const int*)d_in[5];
    const int*    ej   = (const int*)d_in[6];
    const int N = in_sizes[1];
    const int E = in_sizes[4];

    // ws layout (floats): M[3N] | gradRho[2N] | vd[2N] | nd[4N]
    float*  M       = (float*)d_ws;
    float*  gradRho = M + (size_t)N * 3;
    float2* vd      = (float2*)(M + (size_t)N * 5);
    float4* nd      = (float4*)(M + (size_t)N * 7);
    float*  out     = (float*)d_out;

    hipMemsetAsync(M, 0, (size_t)N * 5 * sizeof(float), stream);   // M + gradRho
    hipMemsetAsync(out, 0, (size_t)N * sizeof(float), stream);

    const int tb = 256;
    const int T  = (E + 3) / 4;                 // threads for edge kernels (4 edges each)
    const int gE = (T + tb - 1) / tb;
    const int gN = (N + tb - 1) / tb;

    k_edge_M4       <<<gE, tb, 0, stream>>>(dirs, qarr, ei, ej, vol, M, E);
    k_node_pinv_pack<<<gN, tb, 0, stream>>>(M, vol, dens, vd, N);
    k_edge_gradRho4 <<<gE, tb, 0, stream>>>(dirs, qarr, ei, ej, vd, M, gradRho, E);
    k_pack_nd       <<<gN, tb, 0, stream>>>(vol, dens, (const float2*)gradRho, nd, N);
    k_edge_out4     <<<gE, tb, 0, stream>>>(dirs, qarr, ei, ej, nd, out, E);
}